// Round 3
// baseline (403.677 us; speedup 1.0000x reference)
//
#include <hip/hip_runtime.h>
#include <math.h>

// Problem constants
#define M_ 16
#define N_ 4096
#define D_ 128
#define P_ 8192
#define H_ 32

// Projection tiling
#define NIC 32
#define ICH (N_/NIC)
#define NCB 8

// Attention chunking
#define CHUNK 256
#define NCH (P_/CHUNK)
#define NCH1 (NCH+1)

// Workspace layout (float offsets)
#define QKV_SZ    (3*H_*M_*D_)
#define PART_OFF  (QKV_SZ)
#define OPART_OFF (QKV_SZ)
#define OPART_SZ  (H_*NCH1*M_*D_)
#define ML_OFF    (OPART_OFF + OPART_SZ)

// raw sync helpers (counted vmcnt pipeline)
#define BAR()       asm volatile("s_barrier" ::: "memory")
#define WAIT_VM4()  asm volatile("s_waitcnt vmcnt(4)" ::: "memory")
#define WAIT_VM2()  asm volatile("s_waitcnt vmcnt(2)" ::: "memory")
#define WAIT_VM0()  asm volatile("s_waitcnt vmcnt(0)" ::: "memory")
#define WAIT_LGKM() asm volatile("s_waitcnt lgkmcnt(0)" ::: "memory")

__device__ __forceinline__ void gl_lds16(const float* src, float* dst) {
  __builtin_amdgcn_global_load_lds(
      (const __attribute__((address_space(1))) void*)src,
      (__attribute__((address_space(3))) void*)dst, 16, 0, 0);
}

// ---------------------------------------------------------------------------
// Kernel 1: partial QKV projection. grid (NCB, NIC, 3), block 256. (unchanged)
// ---------------------------------------------------------------------------
__global__ __launch_bounds__(256) void k_proj(const float* __restrict__ X,
                                              const float* __restrict__ Wq,
                                              const float* __restrict__ Wk,
                                              const float* __restrict__ Wv,
                                              float* __restrict__ part) {
  const int mat = blockIdx.z;
  const float* __restrict__ W = (mat == 0) ? Wq : ((mat == 1) ? Wk : Wv);
  const int cb = blockIdx.x, ic = blockIdx.y;
  const int t = threadIdx.x;
  const int j0 = cb * 512 + t * 2;
  const int i0 = ic * ICH;

  __shared__ __align__(16) float XT[ICH][20];

  {
    const int i_l = t & 127, mh = t >> 7;
#pragma unroll
    for (int r = 0; r < 8; ++r)
      XT[i_l][mh * 8 + r] = X[(size_t)(mh * 8 + r) * N_ + i0 + i_l];
  }
  __syncthreads();

  float acc[16][2];
#pragma unroll
  for (int m = 0; m < 16; ++m) { acc[m][0] = 0.f; acc[m][1] = 0.f; }

#pragma unroll 4
  for (int i = 0; i < ICH; ++i) {
    const float2 w = *reinterpret_cast<const float2*>(W + (size_t)(i0 + i) * N_ + j0);
    float xr[16];
    {
      float4 xv;
      xv = *reinterpret_cast<const float4*>(&XT[i][0]);
      xr[0] = xv.x; xr[1] = xv.y; xr[2] = xv.z; xr[3] = xv.w;
      xv = *reinterpret_cast<const float4*>(&XT[i][4]);
      xr[4] = xv.x; xr[5] = xv.y; xr[6] = xv.z; xr[7] = xv.w;
      xv = *reinterpret_cast<const float4*>(&XT[i][8]);
      xr[8] = xv.x; xr[9] = xv.y; xr[10] = xv.z; xr[11] = xv.w;
      xv = *reinterpret_cast<const float4*>(&XT[i][12]);
      xr[12] = xv.x; xr[13] = xv.y; xr[14] = xv.z; xr[15] = xv.w;
    }
#pragma unroll
    for (int m = 0; m < 16; ++m) {
      acc[m][0] = fmaf(xr[m], w.x, acc[m][0]);
      acc[m][1] = fmaf(xr[m], w.y, acc[m][1]);
    }
  }

#pragma unroll
  for (int m = 0; m < 16; ++m) {
    float2 o; o.x = acc[m][0]; o.y = acc[m][1];
    *reinterpret_cast<float2*>(&part[(size_t)((mat * NIC + ic) * M_ + m) * N_ + j0]) = o;
  }
}

// ---------------------------------------------------------------------------
// Kernel 2: reduce partials, RMS-norm q/k, relayout. (unchanged)
// ---------------------------------------------------------------------------
__global__ __launch_bounds__(256) void k_reduce(const float* __restrict__ part,
                                                float* __restrict__ qkv) {
  const int mat = blockIdx.z, m = blockIdx.y, nc = blockIdx.x;
  const int t = threadIdx.x;
  const int n = nc * 256 + t;

  float s = 0.f;
#pragma unroll
  for (int ic = 0; ic < NIC; ++ic)
    s += part[(size_t)((mat * NIC + ic) * M_ + m) * N_ + n];

  float ss = s * s;
#pragma unroll
  for (int off = 1; off < 64; off <<= 1) ss += __shfl_xor(ss, off);
  __shared__ float wsum[4];
  const int wave = t >> 6, lane = t & 63;
  if (lane == 0) wsum[wave] = ss;
  __syncthreads();
  const int half = t >> 7;
  const float tot = wsum[half * 2] + wsum[half * 2 + 1];
  const float scale = (mat < 2) ? rsqrtf(tot * (1.0f / 128.0f)) : 1.0f;

  const int h = n >> 7, d = n & 127;
  qkv[(size_t)((mat * H_ + h) * M_ + m) * D_ + d] = s * scale;
}

// ---------------------------------------------------------------------------
// Kernel 3: fused online-softmax split-P attention. grid (NCH1, H_), block 512.
//
// 8 subtiles of 32 rows. K/V tiles (16KB each) in a ring-3 (48KB) staged via
// global_load_lds (2 insts/wave/stage, rows wave*4..+4), rotation swizzle
// slot=(b+row)&31 applied via pre-swizzled global source. Stage s -> slot s%3,
// stage s+3 issued right after stage s is consumed; steady-state wait is
// vmcnt(4) (2 stages x 2 insts in flight) -> prefetch distance 1.5 subtiles.
//
// Scores: m-split (wave w owns m=2w..2w+1, q in regs). Online max/exp in regs;
// weights exchanged through wbuf[32][20] (+fbuf rescale factors).
// PV: p-split (wave w owns rows w*4..+4 of each subtile -> V tile rows it
// alone staged: no barrier needed for V). O partials combined in dead ring.
// ---------------------------------------------------------------------------
__global__ __launch_bounds__(512, 4) void k_attn(const float* __restrict__ cacheK,
                                                 const float* __restrict__ cacheV,
                                                 const float* __restrict__ qkv,
                                                 float* __restrict__ opart,
                                                 float* __restrict__ ml) {
  const int c = blockIdx.x, h = blockIdx.y;
  const int t = threadIdx.x;
  const int wave = t >> 6, lane = t & 63;
  const int valid = (c < NCH) ? CHUNK : M_;
  const float* __restrict__ Ksrc = (c < NCH)
      ? (cacheK + ((size_t)h * P_ + (size_t)c * CHUNK) * D_)
      : (qkv + (size_t)((1 * H_ + h) * M_) * D_);
  const float* __restrict__ Vsrc = (c < NCH)
      ? (cacheV + ((size_t)h * P_ + (size_t)c * CHUNK) * D_)
      : (qkv + (size_t)((2 * H_ + h) * M_) * D_);

  __shared__ __align__(16) float ring[3 * 32 * 128];  // 48 KB
  __shared__ __align__(16) float wbuf[32 * 20];       // 2.5 KB weights [row][m]
  __shared__ __align__(16) float fbuf[16];            // rescale factor per m

  const int pg = (lane >> 3) & 7, dq = lane & 7;      // scores mapping
  const int b31 = lane & 31, rh = lane >> 5;          // PV mapping
  const int m0 = wave * 2;

  // q -> regs: qr[mi][dd] = q[m0+mi][dq*4 + dd*32 ..+4)
  float4 qr[2][4];
  {
    const float* qb = qkv + (size_t)((0 * H_ + h) * M_) * D_;
#pragma unroll
    for (int mi = 0; mi < 2; ++mi)
#pragma unroll
      for (int dd = 0; dd < 4; ++dd)
        qr[mi][dd] = *reinterpret_cast<const float4*>(qb + (m0 + mi) * D_ + dq * 4 + dd * 32);
  }
  WAIT_VM0();  // drain q loads: all later vmem is manually counted staging

  // STAGE(sub, isV, slot): wave stages its rows [wave*4, wave*4+4) = 2 insts.
  auto STAGE = [&](int sub, int isV, int slot) {
    const float* sb = isV ? Vsrc : Ksrc;
    float* tb = &ring[slot * 4096];
#pragma unroll
    for (int k = 0; k < 2; ++k) {
      const int row = wave * 4 + k * 2 + (lane >> 5);
      int gp = sub * 32 + row; gp = (gp < valid) ? gp : (valid - 1);
      const int b = ((lane & 31) - row) & 31;
      gl_lds16(sb + (size_t)gp * D_ + b * 4, tb + (wave * 4 + k * 2) * D_);
    }
  };

  STAGE(0, 0, 0);  // K0
  STAGE(0, 1, 1);  // V0
  STAGE(1, 0, 2);  // K1

  float mrun[2] = {-3.0e38f, -3.0e38f};
  float lrun[2] = {0.f, 0.f};
  float4 macc[8];
#pragma unroll
  for (int i = 0; i < 8; ++i) macc[i] = make_float4(0.f, 0.f, 0.f, 0.f);

  int sA = 0;  // ring slot of K_st; V_st is at (sA+1)%3
#pragma unroll 1
  for (int st = 0; st < 8; ++st) {
    const int sB = (sA + 1 < 3) ? sA + 1 : sA - 2;

    // ---- scores on K_st ----
    if (st == 7) { WAIT_VM2(); } else { WAIT_VM4(); }
    BAR();
    const float* tile = &ring[sA * 4096];
    float a[2][4];
#pragma unroll
    for (int mi = 0; mi < 2; ++mi)
#pragma unroll
      for (int pi = 0; pi < 4; ++pi) a[mi][pi] = 0.f;

#pragma unroll
    for (int pi = 0; pi < 4; ++pi) {
      const int row = pg + 8 * pi;
#pragma unroll
      for (int dd = 0; dd < 4; ++dd) {
        const int slot = ((dq + 8 * dd) + row) & 31;
        const float4 kk = *reinterpret_cast<const float4*>(tile + row * D_ + slot * 4);
#pragma unroll
        for (int mi = 0; mi < 2; ++mi) {
          a[mi][pi] = fmaf(qr[mi][dd].x, kk.x, a[mi][pi]);
          a[mi][pi] = fmaf(qr[mi][dd].y, kk.y, a[mi][pi]);
          a[mi][pi] = fmaf(qr[mi][dd].z, kk.z, a[mi][pi]);
          a[mi][pi] = fmaf(qr[mi][dd].w, kk.w, a[mi][pi]);
        }
      }
    }
    // reduce d-split over the 8 dq lanes
#pragma unroll
    for (int off = 1; off < 8; off <<= 1)
#pragma unroll
      for (int mi = 0; mi < 2; ++mi)
#pragma unroll
        for (int pi = 0; pi < 4; ++pi)
          a[mi][pi] += __shfl_xor(a[mi][pi], off);

    // mask invalid rows (chunk 32 tail)
    const int pb = st * 32;
#pragma unroll
    for (int pi = 0; pi < 4; ++pi) {
      if (pb + pg + 8 * pi >= valid) {
        a[0][pi] = -3.0e38f;
        a[1][pi] = -3.0e38f;
      }
    }

    // online softmax update for this wave's 2 m's
    float w[2][4], fac[2];
#pragma unroll
    for (int mi = 0; mi < 2; ++mi) {
      float tmax = fmaxf(fmaxf(a[mi][0], a[mi][1]), fmaxf(a[mi][2], a[mi][3]));
      tmax = fmaxf(tmax, __shfl_xor(tmax, 8));
      tmax = fmaxf(tmax, __shfl_xor(tmax, 16));
      tmax = fmaxf(tmax, __shfl_xor(tmax, 32));
      const float mnew = fmaxf(mrun[mi], tmax);
      fac[mi] = __expf(mrun[mi] - mnew);
      mrun[mi] = mnew;
      float rs = 0.f;
#pragma unroll
      for (int pi = 0; pi < 4; ++pi) {
        w[mi][pi] = __expf(a[mi][pi] - mnew);
        rs += w[mi][pi];
      }
      rs += __shfl_xor(rs, 8);
      rs += __shfl_xor(rs, 16);
      rs += __shfl_xor(rs, 32);
      lrun[mi] = lrun[mi] * fac[mi] + rs;
    }
    // publish weights + factors
#pragma unroll
    for (int mi = 0; mi < 2; ++mi) {
      if (dq == mi) {
#pragma unroll
        for (int pi = 0; pi < 4; ++pi)
          wbuf[(pg + 8 * pi) * 20 + m0 + mi] = w[mi][pi];
        if (pg == 0) fbuf[m0 + mi] = fac[mi];
      }
    }
    WAIT_LGKM();  // my ds reads (K tile) + writes (wbuf/fbuf) done
    BAR();        // K_st slot free block-wide; wbuf/fbuf visible
    if (st <= 6) STAGE(st + 1, 1, sA);  // V_{st+1} into freed K slot

    // ---- PV on V_st (wave-private rows -> no barrier) ----
    if (st == 7) { WAIT_VM0(); } else { WAIT_VM4(); }
    const float* vt = &ring[sB * 4096];
    {
      const float4 f0 = *reinterpret_cast<const float4*>(&fbuf[rh * 8]);
      const float4 f1 = *reinterpret_cast<const float4*>(&fbuf[rh * 8 + 4]);
#define RSC(i, ff) macc[i].x *= ff; macc[i].y *= ff; macc[i].z *= ff; macc[i].w *= ff;
      RSC(0, f0.x) RSC(1, f0.y) RSC(2, f0.z) RSC(3, f0.w)
      RSC(4, f1.x) RSC(5, f1.y) RSC(6, f1.z) RSC(7, f1.w)
#undef RSC
    }
#pragma unroll
    for (int j = 0; j < 4; ++j) {
      const int row = wave * 4 + j;
      const int slot = (b31 + row) & 31;
      const float4 v4 = *reinterpret_cast<const float4*>(vt + row * D_ + slot * 4);
      const float4 wf0 = *reinterpret_cast<const float4*>(&wbuf[row * 20 + rh * 8]);
      const float4 wf1 = *reinterpret_cast<const float4*>(&wbuf[row * 20 + rh * 8 + 4]);
#define PVROW(i, wc) \
      macc[i].x = fmaf(wc, v4.x, macc[i].x); \
      macc[i].y = fmaf(wc, v4.y, macc[i].y); \
      macc[i].z = fmaf(wc, v4.z, macc[i].z); \
      macc[i].w = fmaf(wc, v4.w, macc[i].w);
      PVROW(0, wf0.x) PVROW(1, wf0.y) PVROW(2, wf0.z) PVROW(3, wf0.w)
      PVROW(4, wf1.x) PVROW(5, wf1.y) PVROW(6, wf1.z) PVROW(7, wf1.w)
#undef PVROW
    }
    WAIT_LGKM();  // my V reads done before overwriting my rows
    if (st <= 5) STAGE(st + 2, 0, sB);  // K_{st+2} into freed V slot

    sA += 2; if (sA >= 3) sA -= 3;
  }

  // ---- Epilogue: combine 8 wave partials through dead ring ----
  WAIT_LGKM(); BAR();
  float* ep = ring;  // 4 buffers x 2048 floats (32 KB)
  if (wave < 4) {
#pragma unroll
    for (int mm = 0; mm < 8; ++mm)
      *reinterpret_cast<float4*>(ep + wave * 2048 + (rh * 8 + mm) * D_ + b31 * 4) = macc[mm];
  }
  WAIT_LGKM(); BAR();
  if (wave >= 4) {
#pragma unroll
    for (int mm = 0; mm < 8; ++mm) {
      float4* p = reinterpret_cast<float4*>(ep + (wave - 4) * 2048 + (rh * 8 + mm) * D_ + b31 * 4);
      float4 v = *p;
      v.x += macc[mm].x; v.y += macc[mm].y; v.z += macc[mm].z; v.w += macc[mm].w;
      *p = v;
    }
  }
  WAIT_LGKM(); BAR();
  {
    const size_t base = (size_t)((h * NCH1 + c) * M_) * D_;
    const float4* e4 = reinterpret_cast<const float4*>(ep);
    const float4 s0 = e4[t], s1 = e4[t + 512], s2 = e4[t + 1024], s3 = e4[t + 1536];
    float4 o;
    o.x = s0.x + s1.x + s2.x + s3.x;
    o.y = s0.y + s1.y + s2.y + s3.y;
    o.z = s0.z + s1.z + s2.z + s3.z;
    o.w = s0.w + s1.w + s2.w + s3.w;
    reinterpret_cast<float4*>(opart + base)[t] = o;
    // per-m running stats from owner wave (lane pg==0, dq==mi)
#pragma unroll
    for (int mi = 0; mi < 2; ++mi) {
      if (pg == 0 && dq == mi) {
        ml[((size_t)(h * NCH1 + c) * M_ + m0 + mi) * 2 + 0] = mrun[mi];
        ml[((size_t)(h * NCH1 + c) * M_ + m0 + mi) * 2 + 1] = lrun[mi];
      }
    }
  }
}

// ---------------------------------------------------------------------------
// Kernel 4: combine 33 chunk partials per (h, m). (unchanged)
// ---------------------------------------------------------------------------
__global__ __launch_bounds__(128) void k_comb(const float* __restrict__ opart,
                                              const float* __restrict__ ml,
                                              float* __restrict__ out) {
  const int m = blockIdx.x, h = blockIdx.y, t = threadIdx.x;
  __shared__ float Ms[NCH1], Ls[NCH1];
  if (t < NCH1) {
    Ms[t] = ml[((size_t)(h * NCH1 + t) * M_ + m) * 2 + 0];
    Ls[t] = ml[((size_t)(h * NCH1 + t) * M_ + m) * 2 + 1];
  }
  __syncthreads();
  float gM = -3.0e38f;
#pragma unroll
  for (int c2 = 0; c2 < NCH1; ++c2) gM = fmaxf(gM, Ms[c2]);
  float T = 0.f, o = 0.f;
  for (int c2 = 0; c2 < NCH1; ++c2) {
    const float f = __expf(Ms[c2] - gM);
    T = fmaf(Ls[c2], f, T);
    o = fmaf(opart[((size_t)(h * NCH1 + c2) * M_ + m) * D_ + t], f, o);
  }
  out[(size_t)m * N_ + h * D_ + t] = o / T;
}

// ---------------------------------------------------------------------------
extern "C" void kernel_launch(void* const* d_in, const int* in_sizes, int n_in,
                              void* d_out, int out_size, void* d_ws, size_t ws_size,
                              hipStream_t stream) {
  const float* X  = (const float*)d_in[0];
  const float* Wq = (const float*)d_in[1];
  const float* Wk = (const float*)d_in[2];
  const float* Wv = (const float*)d_in[3];
  const float* cK = (const float*)d_in[4];
  const float* cV = (const float*)d_in[5];
  float* ws    = (float*)d_ws;
  float* qkv   = ws;
  float* part  = ws + PART_OFF;
  float* opart = ws + OPART_OFF;
  float* mlbuf = ws + ML_OFF;
  float* out   = (float*)d_out;

  hipLaunchKernelGGL(k_proj,   dim3(NCB, NIC, 3), dim3(256), 0, stream, X, Wq, Wk, Wv, part);
  hipLaunchKernelGGL(k_reduce, dim3(16, M_, 3),   dim3(256), 0, stream, part, qkv);
  hipLaunchKernelGGL(k_attn,   dim3(NCH1, H_),    dim3(512), 0, stream, cK, cV, qkv, opart, mlbuf);
  hipLaunchKernelGGL(k_comb,   dim3(M_, H_),      dim3(128), 0, stream, opart, mlbuf, out);
}

// Round 4
// 201.812 us; speedup vs baseline: 2.0003x; 2.0003x over previous
//
#include <hip/hip_runtime.h>
#include <math.h>

// Problem constants
#define M_ 16
#define N_ 4096
#define D_ 128
#define P_ 8192
#define H_ 32

// Projection tiling
#define NIC 32
#define ICH (N_/NIC)
#define NCB 8

// Attention chunking
#define CHUNK 256
#define NCH (P_/CHUNK)
#define NCH1 (NCH+1)

// Workspace layout (float offsets)
#define QKV_SZ    (3*H_*M_*D_)
#define PART_OFF  (QKV_SZ)
#define OPART_OFF (QKV_SZ)
#define OPART_SZ  (H_*NCH1*M_*D_)
#define ML_OFF    (OPART_OFF + OPART_SZ)

// raw sync helpers (counted vmcnt pipeline)
#define BAR()       asm volatile("s_barrier" ::: "memory")
#define WAIT_VM4()  asm volatile("s_waitcnt vmcnt(4)" ::: "memory")
#define WAIT_VM2()  asm volatile("s_waitcnt vmcnt(2)" ::: "memory")
#define WAIT_VM0()  asm volatile("s_waitcnt vmcnt(0)" ::: "memory")
#define WAIT_LGKM() asm volatile("s_waitcnt lgkmcnt(0)" ::: "memory")

__device__ __forceinline__ void gl_lds16(const float* src, float* dst) {
  __builtin_amdgcn_global_load_lds(
      (const __attribute__((address_space(1))) void*)src,
      (__attribute__((address_space(3))) void*)dst, 16, 0, 0);
}

// ---------------------------------------------------------------------------
// Kernel 1: partial QKV projection. grid (NCB, NIC, 3), block 256. (unchanged)
// ---------------------------------------------------------------------------
__global__ __launch_bounds__(256) void k_proj(const float* __restrict__ X,
                                              const float* __restrict__ Wq,
                                              const float* __restrict__ Wk,
                                              const float* __restrict__ Wv,
                                              float* __restrict__ part) {
  const int mat = blockIdx.z;
  const float* __restrict__ W = (mat == 0) ? Wq : ((mat == 1) ? Wk : Wv);
  const int cb = blockIdx.x, ic = blockIdx.y;
  const int t = threadIdx.x;
  const int j0 = cb * 512 + t * 2;
  const int i0 = ic * ICH;

  __shared__ __align__(16) float XT[ICH][20];

  {
    const int i_l = t & 127, mh = t >> 7;
#pragma unroll
    for (int r = 0; r < 8; ++r)
      XT[i_l][mh * 8 + r] = X[(size_t)(mh * 8 + r) * N_ + i0 + i_l];
  }
  __syncthreads();

  float acc[16][2];
#pragma unroll
  for (int m = 0; m < 16; ++m) { acc[m][0] = 0.f; acc[m][1] = 0.f; }

#pragma unroll 4
  for (int i = 0; i < ICH; ++i) {
    const float2 w = *reinterpret_cast<const float2*>(W + (size_t)(i0 + i) * N_ + j0);
    float xr[16];
    {
      float4 xv;
      xv = *reinterpret_cast<const float4*>(&XT[i][0]);
      xr[0] = xv.x; xr[1] = xv.y; xr[2] = xv.z; xr[3] = xv.w;
      xv = *reinterpret_cast<const float4*>(&XT[i][4]);
      xr[4] = xv.x; xr[5] = xv.y; xr[6] = xv.z; xr[7] = xv.w;
      xv = *reinterpret_cast<const float4*>(&XT[i][8]);
      xr[8] = xv.x; xr[9] = xv.y; xr[10] = xv.z; xr[11] = xv.w;
      xv = *reinterpret_cast<const float4*>(&XT[i][12]);
      xr[12] = xv.x; xr[13] = xv.y; xr[14] = xv.z; xr[15] = xv.w;
    }
#pragma unroll
    for (int m = 0; m < 16; ++m) {
      acc[m][0] = fmaf(xr[m], w.x, acc[m][0]);
      acc[m][1] = fmaf(xr[m], w.y, acc[m][1]);
    }
  }

#pragma unroll
  for (int m = 0; m < 16; ++m) {
    float2 o; o.x = acc[m][0]; o.y = acc[m][1];
    *reinterpret_cast<float2*>(&part[(size_t)((mat * NIC + ic) * M_ + m) * N_ + j0]) = o;
  }
}

// ---------------------------------------------------------------------------
// Kernel 2: reduce partials, RMS-norm q/k, relayout. (unchanged)
// ---------------------------------------------------------------------------
__global__ __launch_bounds__(256) void k_reduce(const float* __restrict__ part,
                                                float* __restrict__ qkv) {
  const int mat = blockIdx.z, m = blockIdx.y, nc = blockIdx.x;
  const int t = threadIdx.x;
  const int n = nc * 256 + t;

  float s = 0.f;
#pragma unroll
  for (int ic = 0; ic < NIC; ++ic)
    s += part[(size_t)((mat * NIC + ic) * M_ + m) * N_ + n];

  float ss = s * s;
#pragma unroll
  for (int off = 1; off < 64; off <<= 1) ss += __shfl_xor(ss, off);
  __shared__ float wsum[4];
  const int wave = t >> 6, lane = t & 63;
  if (lane == 0) wsum[wave] = ss;
  __syncthreads();
  const int half = t >> 7;
  const float tot = wsum[half * 2] + wsum[half * 2 + 1];
  const float scale = (mat < 2) ? rsqrtf(tot * (1.0f / 128.0f)) : 1.0f;

  const int h = n >> 7, d = n & 127;
  qkv[(size_t)((mat * H_ + h) * M_ + m) * D_ + d] = s * scale;
}

// ---------------------------------------------------------------------------
// Kernel 3: fused online-softmax split-P attention. grid (NCH1, H_), block 512.
// Identical structure to round 3; ONLY change is __launch_bounds__(512, 2)
// (was (512,4) -> allocator clamped to 64 VGPR and spilled ~50 regs/thread to
// scratch: WRITE_SIZE 322MB, FETCH +370MB. Demand is ~110-130 VGPR.)
// ---------------------------------------------------------------------------
__global__ __launch_bounds__(512, 2) void k_attn(const float* __restrict__ cacheK,
                                                 const float* __restrict__ cacheV,
                                                 const float* __restrict__ qkv,
                                                 float* __restrict__ opart,
                                                 float* __restrict__ ml) {
  const int c = blockIdx.x, h = blockIdx.y;
  const int t = threadIdx.x;
  const int wave = t >> 6, lane = t & 63;
  const int valid = (c < NCH) ? CHUNK : M_;
  const float* __restrict__ Ksrc = (c < NCH)
      ? (cacheK + ((size_t)h * P_ + (size_t)c * CHUNK) * D_)
      : (qkv + (size_t)((1 * H_ + h) * M_) * D_);
  const float* __restrict__ Vsrc = (c < NCH)
      ? (cacheV + ((size_t)h * P_ + (size_t)c * CHUNK) * D_)
      : (qkv + (size_t)((2 * H_ + h) * M_) * D_);

  __shared__ __align__(16) float ring[3 * 32 * 128];  // 48 KB
  __shared__ __align__(16) float wbuf[32 * 20];       // 2.5 KB weights [row][m]
  __shared__ __align__(16) float fbuf[16];            // rescale factor per m

  const int pg = (lane >> 3) & 7, dq = lane & 7;      // scores mapping
  const int b31 = lane & 31, rh = lane >> 5;          // PV mapping
  const int m0 = wave * 2;

  // q -> regs: qr[mi][dd] = q[m0+mi][dq*4 + dd*32 ..+4)
  float4 qr[2][4];
  {
    const float* qb = qkv + (size_t)((0 * H_ + h) * M_) * D_;
#pragma unroll
    for (int mi = 0; mi < 2; ++mi)
#pragma unroll
      for (int dd = 0; dd < 4; ++dd)
        qr[mi][dd] = *reinterpret_cast<const float4*>(qb + (m0 + mi) * D_ + dq * 4 + dd * 32);
  }
  WAIT_VM0();  // drain q loads: all later vmem is manually counted staging

  // STAGE(sub, isV, slot): wave stages its rows [wave*4, wave*4+4) = 2 insts.
  auto STAGE = [&](int sub, int isV, int slot) {
    const float* sb = isV ? Vsrc : Ksrc;
    float* tb = &ring[slot * 4096];
#pragma unroll
    for (int k = 0; k < 2; ++k) {
      const int row = wave * 4 + k * 2 + (lane >> 5);
      int gp = sub * 32 + row; gp = (gp < valid) ? gp : (valid - 1);
      const int b = ((lane & 31) - row) & 31;
      gl_lds16(sb + (size_t)gp * D_ + b * 4, tb + (wave * 4 + k * 2) * D_);
    }
  };

  STAGE(0, 0, 0);  // K0
  STAGE(0, 1, 1);  // V0
  STAGE(1, 0, 2);  // K1

  float mrun[2] = {-3.0e38f, -3.0e38f};
  float lrun[2] = {0.f, 0.f};
  float4 macc[8];
#pragma unroll
  for (int i = 0; i < 8; ++i) macc[i] = make_float4(0.f, 0.f, 0.f, 0.f);

  int sA = 0;  // ring slot of K_st; V_st is at (sA+1)%3
#pragma unroll 1
  for (int st = 0; st < 8; ++st) {
    const int sB = (sA + 1 < 3) ? sA + 1 : sA - 2;

    // ---- scores on K_st ----
    if (st == 7) { WAIT_VM2(); } else { WAIT_VM4(); }
    BAR();
    const float* tile = &ring[sA * 4096];
    float a[2][4];
#pragma unroll
    for (int mi = 0; mi < 2; ++mi)
#pragma unroll
      for (int pi = 0; pi < 4; ++pi) a[mi][pi] = 0.f;

#pragma unroll
    for (int pi = 0; pi < 4; ++pi) {
      const int row = pg + 8 * pi;
#pragma unroll
      for (int dd = 0; dd < 4; ++dd) {
        const int slot = ((dq + 8 * dd) + row) & 31;
        const float4 kk = *reinterpret_cast<const float4*>(tile + row * D_ + slot * 4);
#pragma unroll
        for (int mi = 0; mi < 2; ++mi) {
          a[mi][pi] = fmaf(qr[mi][dd].x, kk.x, a[mi][pi]);
          a[mi][pi] = fmaf(qr[mi][dd].y, kk.y, a[mi][pi]);
          a[mi][pi] = fmaf(qr[mi][dd].z, kk.z, a[mi][pi]);
          a[mi][pi] = fmaf(qr[mi][dd].w, kk.w, a[mi][pi]);
        }
      }
    }
    // reduce d-split over the 8 dq lanes
#pragma unroll
    for (int off = 1; off < 8; off <<= 1)
#pragma unroll
      for (int mi = 0; mi < 2; ++mi)
#pragma unroll
        for (int pi = 0; pi < 4; ++pi)
          a[mi][pi] += __shfl_xor(a[mi][pi], off);

    // mask invalid rows (chunk 32 tail)
    const int pb = st * 32;
#pragma unroll
    for (int pi = 0; pi < 4; ++pi) {
      if (pb + pg + 8 * pi >= valid) {
        a[0][pi] = -3.0e38f;
        a[1][pi] = -3.0e38f;
      }
    }

    // online softmax update for this wave's 2 m's
    float w[2][4], fac[2];
#pragma unroll
    for (int mi = 0; mi < 2; ++mi) {
      float tmax = fmaxf(fmaxf(a[mi][0], a[mi][1]), fmaxf(a[mi][2], a[mi][3]));
      tmax = fmaxf(tmax, __shfl_xor(tmax, 8));
      tmax = fmaxf(tmax, __shfl_xor(tmax, 16));
      tmax = fmaxf(tmax, __shfl_xor(tmax, 32));
      const float mnew = fmaxf(mrun[mi], tmax);
      fac[mi] = __expf(mrun[mi] - mnew);
      mrun[mi] = mnew;
      float rs = 0.f;
#pragma unroll
      for (int pi = 0; pi < 4; ++pi) {
        w[mi][pi] = __expf(a[mi][pi] - mnew);
        rs += w[mi][pi];
      }
      rs += __shfl_xor(rs, 8);
      rs += __shfl_xor(rs, 16);
      rs += __shfl_xor(rs, 32);
      lrun[mi] = lrun[mi] * fac[mi] + rs;
    }
    // publish weights + factors
#pragma unroll
    for (int mi = 0; mi < 2; ++mi) {
      if (dq == mi) {
#pragma unroll
        for (int pi = 0; pi < 4; ++pi)
          wbuf[(pg + 8 * pi) * 20 + m0 + mi] = w[mi][pi];
        if (pg == 0) fbuf[m0 + mi] = fac[mi];
      }
    }
    WAIT_LGKM();  // my ds reads (K tile) + writes (wbuf/fbuf) done
    BAR();        // K_st slot free block-wide; wbuf/fbuf visible
    if (st <= 6) STAGE(st + 1, 1, sA);  // V_{st+1} into freed K slot

    // ---- PV on V_st (wave-private rows -> no barrier) ----
    if (st == 7) { WAIT_VM0(); } else { WAIT_VM4(); }
    const float* vt = &ring[sB * 4096];
    {
      const float4 f0 = *reinterpret_cast<const float4*>(&fbuf[rh * 8]);
      const float4 f1 = *reinterpret_cast<const float4*>(&fbuf[rh * 8 + 4]);
#define RSC(i, ff) macc[i].x *= ff; macc[i].y *= ff; macc[i].z *= ff; macc[i].w *= ff;
      RSC(0, f0.x) RSC(1, f0.y) RSC(2, f0.z) RSC(3, f0.w)
      RSC(4, f1.x) RSC(5, f1.y) RSC(6, f1.z) RSC(7, f1.w)
#undef RSC
    }
#pragma unroll
    for (int j = 0; j < 4; ++j) {
      const int row = wave * 4 + j;
      const int slot = (b31 + row) & 31;
      const float4 v4 = *reinterpret_cast<const float4*>(vt + row * D_ + slot * 4);
      const float4 wf0 = *reinterpret_cast<const float4*>(&wbuf[row * 20 + rh * 8]);
      const float4 wf1 = *reinterpret_cast<const float4*>(&wbuf[row * 20 + rh * 8 + 4]);
#define PVROW(i, wc) \
      macc[i].x = fmaf(wc, v4.x, macc[i].x); \
      macc[i].y = fmaf(wc, v4.y, macc[i].y); \
      macc[i].z = fmaf(wc, v4.z, macc[i].z); \
      macc[i].w = fmaf(wc, v4.w, macc[i].w);
      PVROW(0, wf0.x) PVROW(1, wf0.y) PVROW(2, wf0.z) PVROW(3, wf0.w)
      PVROW(4, wf1.x) PVROW(5, wf1.y) PVROW(6, wf1.z) PVROW(7, wf1.w)
#undef PVROW
    }
    WAIT_LGKM();  // my V reads done before overwriting my rows
    if (st <= 5) STAGE(st + 2, 0, sB);  // K_{st+2} into freed V slot

    sA += 2; if (sA >= 3) sA -= 3;
  }

  // ---- Epilogue: combine 8 wave partials through dead ring ----
  WAIT_LGKM(); BAR();
  float* ep = ring;  // 4 buffers x 2048 floats (32 KB)
  if (wave < 4) {
#pragma unroll
    for (int mm = 0; mm < 8; ++mm)
      *reinterpret_cast<float4*>(ep + wave * 2048 + (rh * 8 + mm) * D_ + b31 * 4) = macc[mm];
  }
  WAIT_LGKM(); BAR();
  if (wave >= 4) {
#pragma unroll
    for (int mm = 0; mm < 8; ++mm) {
      float4* p = reinterpret_cast<float4*>(ep + (wave - 4) * 2048 + (rh * 8 + mm) * D_ + b31 * 4);
      float4 v = *p;
      v.x += macc[mm].x; v.y += macc[mm].y; v.z += macc[mm].z; v.w += macc[mm].w;
      *p = v;
    }
  }
  WAIT_LGKM(); BAR();
  {
    const size_t base = (size_t)((h * NCH1 + c) * M_) * D_;
    const float4* e4 = reinterpret_cast<const float4*>(ep);
    const float4 s0 = e4[t], s1 = e4[t + 512], s2 = e4[t + 1024], s3 = e4[t + 1536];
    float4 o;
    o.x = s0.x + s1.x + s2.x + s3.x;
    o.y = s0.y + s1.y + s2.y + s3.y;
    o.z = s0.z + s1.z + s2.z + s3.z;
    o.w = s0.w + s1.w + s2.w + s3.w;
    reinterpret_cast<float4*>(opart + base)[t] = o;
    // per-m running stats from owner wave (lane pg==0, dq==mi)
#pragma unroll
    for (int mi = 0; mi < 2; ++mi) {
      if (pg == 0 && dq == mi) {
        ml[((size_t)(h * NCH1 + c) * M_ + m0 + mi) * 2 + 0] = mrun[mi];
        ml[((size_t)(h * NCH1 + c) * M_ + m0 + mi) * 2 + 1] = lrun[mi];
      }
    }
  }
}

// ---------------------------------------------------------------------------
// Kernel 4: combine 33 chunk partials per (h, m). (unchanged)
// ---------------------------------------------------------------------------
__global__ __launch_bounds__(128) void k_comb(const float* __restrict__ opart,
                                              const float* __restrict__ ml,
                                              float* __restrict__ out) {
  const int m = blockIdx.x, h = blockIdx.y, t = threadIdx.x;
  __shared__ float Ms[NCH1], Ls[NCH1];
  if (t < NCH1) {
    Ms[t] = ml[((size_t)(h * NCH1 + t) * M_ + m) * 2 + 0];
    Ls[t] = ml[((size_t)(h * NCH1 + t) * M_ + m) * 2 + 1];
  }
  __syncthreads();
  float gM = -3.0e38f;
#pragma unroll
  for (int c2 = 0; c2 < NCH1; ++c2) gM = fmaxf(gM, Ms[c2]);
  float T = 0.f, o = 0.f;
  for (int c2 = 0; c2 < NCH1; ++c2) {
    const float f = __expf(Ms[c2] - gM);
    T = fmaf(Ls[c2], f, T);
    o = fmaf(opart[((size_t)(h * NCH1 + c2) * M_ + m) * D_ + t], f, o);
  }
  out[(size_t)m * N_ + h * D_ + t] = o / T;
}

// ---------------------------------------------------------------------------
extern "C" void kernel_launch(void* const* d_in, const int* in_sizes, int n_in,
                              void* d_out, int out_size, void* d_ws, size_t ws_size,
                              hipStream_t stream) {
  const float* X  = (const float*)d_in[0];
  const float* Wq = (const float*)d_in[1];
  const float* Wk = (const float*)d_in[2];
  const float* Wv = (const float*)d_in[3];
  const float* cK = (const float*)d_in[4];
  const float* cV = (const float*)d_in[5];
  float* ws    = (float*)d_ws;
  float* qkv   = ws;
  float* part  = ws + PART_OFF;
  float* opart = ws + OPART_OFF;
  float* mlbuf = ws + ML_OFF;
  float* out   = (float*)d_out;

  hipLaunchKernelGGL(k_proj,   dim3(NCB, NIC, 3), dim3(256), 0, stream, X, Wq, Wk, Wv, part);
  hipLaunchKernelGGL(k_reduce, dim3(16, M_, 3),   dim3(256), 0, stream, part, qkv);
  hipLaunchKernelGGL(k_attn,   dim3(NCH1, H_),    dim3(512), 0, stream, cK, cV, qkv, opart, mlbuf);
  hipLaunchKernelGGL(k_comb,   dim3(M_, H_),      dim3(128), 0, stream, opart, mlbuf, out);
}